// Round 2
// baseline (812.535 us; speedup 1.0000x reference)
//
#include <hip/hip_runtime.h>

#define N_NODES 50000
#define N_EDGES 800000
#define HID 128

// ---------------- CSR build ----------------
__global__ void hist_kernel(const int* __restrict__ dst, int* __restrict__ counts) {
    int e = blockIdx.x * 256 + threadIdx.x;
    if (e < N_EDGES) atomicAdd(&counts[dst[e]], 1);
}

__global__ void scan_block_kernel(const int* __restrict__ counts, int* __restrict__ excl,
                                  int* __restrict__ blockSums) {
    __shared__ int s[512];
    int t = threadIdx.x;
    int i = blockIdx.x * 512 + t;
    int v = (i < N_NODES) ? counts[i] : 0;
    s[t] = v;
    __syncthreads();
    for (int off = 1; off < 512; off <<= 1) {
        int add = (t >= off) ? s[t - off] : 0;
        __syncthreads();
        s[t] += add;
        __syncthreads();
    }
    if (i < N_NODES) excl[i] = s[t] - v;
    if (t == 511) blockSums[blockIdx.x] = s[511];
}

__global__ void scan_sums_kernel(const int* __restrict__ blockSums, int* __restrict__ blockOff,
                                 int nb) {
    __shared__ int s[128];
    int t = threadIdx.x;
    int v = (t < nb) ? blockSums[t] : 0;
    s[t] = v;
    __syncthreads();
    for (int off = 1; off < 128; off <<= 1) {
        int add = (t >= off) ? s[t - off] : 0;
        __syncthreads();
        s[t] += add;
        __syncthreads();
    }
    if (t < nb) blockOff[t] = s[t] - v;
}

__global__ void add_off_kernel(int* __restrict__ excl, const int* __restrict__ blockOff) {
    int i = blockIdx.x * 256 + threadIdx.x;
    if (i < N_NODES) excl[i] += blockOff[i >> 9];
}

__global__ void scatter_kernel(const int* __restrict__ src, const int* __restrict__ dst,
                               const int* __restrict__ row_start, int* __restrict__ cursor,
                               int* __restrict__ col) {
    int e = blockIdx.x * 256 + threadIdx.x;
    if (e < N_EDGES) {
        int d = dst[e];
        int p = atomicAdd(&cursor[d], 1);
        col[row_start[d] + p] = src[e];
    }
}

// ---------------- embedding ----------------
__global__ void embed_kernel(const int* __restrict__ feats, const float* __restrict__ key_emb,
                             const float* __restrict__ val_emb, float* __restrict__ h) {
    int idx = blockIdx.x * 256 + threadIdx.x;   // one float4 of one node row
    if (idx >= N_NODES * 32) return;
    int n = idx >> 5, q = idx & 31;
    int f0 = feats[2 * n], f1 = feats[2 * n + 1];
    float4 a = ((const float4*)key_emb)[f0 * 32 + q];
    float4 b = ((const float4*)val_emb)[f1 * 32 + q];
    float4 r;
    r.x = fmaxf(a.x + b.x, 0.f);
    r.y = fmaxf(a.y + b.y, 0.f);
    r.z = fmaxf(a.z + b.z, 0.f);
    r.w = fmaxf(a.w + b.w, 0.f);
    ((float4*)h)[idx] = r;
}

// ---------------- fused GIN layer: gather + 2-layer MLP (+ classifier if LAST) ----
// 64-row tile in 32KB LDS; thread = 4 cols x 8 rows register block.
// z reads are 2-way broadcast ds_read_b128 (conflict-free).
template <bool LAST>
__global__ __launch_bounds__(256) void layer_kernel(
    const float* __restrict__ hin, float* __restrict__ hout,
    const int* __restrict__ row_start, const int* __restrict__ counts,
    const int* __restrict__ col,
    const float* __restrict__ W1, const float* __restrict__ b1,
    const float* __restrict__ W2, const float* __restrict__ b2,
    const float* __restrict__ Wc, float* __restrict__ out) {
    __shared__ float zt[64][128];                 // 32 KB
    __shared__ float wcs[LAST ? 40 * 136 : 1];    // 21.8 KB, last layer only
    int t = threadIdx.x;
    int row0 = blockIdx.x * 64;
    int w = t >> 6, lane = t & 63;

    // ---- stage: z = h + sum_{u in N(node)} h[u], gathered straight into LDS ----
    {
        const float2* hp = (const float2*)hin;
        for (int r = w * 16; r < w * 16 + 16; ++r) {
            int node = row0 + r;
            float2 acc = make_float2(0.f, 0.f);
            if (node < N_NODES) {
                acc = hp[(size_t)node * 64 + lane];
                int s = row_start[node];
                int c = counts[node];
                int j = 0;
                for (; j + 4 <= c; j += 4) {
                    int u0 = col[s + j], u1 = col[s + j + 1];
                    int u2 = col[s + j + 2], u3 = col[s + j + 3];
                    float2 v0 = hp[(size_t)u0 * 64 + lane];
                    float2 v1 = hp[(size_t)u1 * 64 + lane];
                    float2 v2 = hp[(size_t)u2 * 64 + lane];
                    float2 v3 = hp[(size_t)u3 * 64 + lane];
                    acc.x += v0.x + v1.x + v2.x + v3.x;
                    acc.y += v0.y + v1.y + v2.y + v3.y;
                }
                for (; j < c; ++j) {
                    int u = col[s + j];
                    float2 v = hp[(size_t)u * 64 + lane];
                    acc.x += v.x;
                    acc.y += v.y;
                }
            }
            *(float2*)&zt[r][lane * 2] = acc;
        }
    }
    __syncthreads();

    int cg = t & 31, rg = t >> 5;   // 32 col-groups x 8 row-groups
    int c0 = cg * 4;
    float acc[4][8];

    // ---- phase 1: z1 = relu(z @ W1^T + b1) ----
    {
        float4 bv = ((const float4*)b1)[cg];
#pragma unroll
        for (int r = 0; r < 8; ++r) {
            acc[0][r] = bv.x; acc[1][r] = bv.y; acc[2][r] = bv.z; acc[3][r] = bv.w;
        }
        for (int k4 = 0; k4 < 32; ++k4) {
            float4 wv[4];
#pragma unroll
            for (int j = 0; j < 4; ++j)
                wv[j] = *(const float4*)&W1[(size_t)(c0 + j) * HID + k4 * 4];
#pragma unroll
            for (int r = 0; r < 8; ++r) {
                float4 zv = *(const float4*)&zt[rg * 8 + r][k4 * 4];
#pragma unroll
                for (int j = 0; j < 4; ++j)
                    acc[j][r] += zv.x * wv[j].x + zv.y * wv[j].y + zv.z * wv[j].z + zv.w * wv[j].w;
            }
        }
    }
    __syncthreads();
#pragma unroll
    for (int r = 0; r < 8; ++r) {
        float4 v = make_float4(fmaxf(acc[0][r], 0.f), fmaxf(acc[1][r], 0.f),
                               fmaxf(acc[2][r], 0.f), fmaxf(acc[3][r], 0.f));
        *(float4*)&zt[rg * 8 + r][c0] = v;
    }
    __syncthreads();

    // ---- phase 2: h = z1 @ W2^T + b2 ----
    {
        float4 bv = ((const float4*)b2)[cg];
#pragma unroll
        for (int r = 0; r < 8; ++r) {
            acc[0][r] = bv.x; acc[1][r] = bv.y; acc[2][r] = bv.z; acc[3][r] = bv.w;
        }
        for (int k4 = 0; k4 < 32; ++k4) {
            float4 wv[4];
#pragma unroll
            for (int j = 0; j < 4; ++j)
                wv[j] = *(const float4*)&W2[(size_t)(c0 + j) * HID + k4 * 4];
#pragma unroll
            for (int r = 0; r < 8; ++r) {
                float4 zv = *(const float4*)&zt[rg * 8 + r][k4 * 4];
#pragma unroll
                for (int j = 0; j < 4; ++j)
                    acc[j][r] += zv.x * wv[j].x + zv.y * wv[j].y + zv.z * wv[j].z + zv.w * wv[j].w;
            }
        }
    }

    if constexpr (!LAST) {
#pragma unroll
        for (int r = 0; r < 8; ++r) {
            int node = row0 + rg * 8 + r;
            if (node < N_NODES)
                *(float4*)&hout[(size_t)node * HID + c0] =
                    make_float4(acc[0][r], acc[1][r], acc[2][r], acc[3][r]);
        }
    } else {
        // ---- phase 3: out = h @ Wc^T, h kept in LDS (never hits HBM) ----
        __syncthreads();   // all phase-2 zt reads done
#pragma unroll
        for (int r = 0; r < 8; ++r)
            *(float4*)&zt[rg * 8 + r][c0] =
                make_float4(acc[0][r], acc[1][r], acc[2][r], acc[3][r]);
        for (int i = t; i < 40 * 32; i += 256) {
            int c = i >> 5, q = i & 31;
            *(float4*)&wcs[c * 136 + q * 4] = ((const float4*)Wc)[i];
        }
        __syncthreads();
        for (int r = w * 16; r < w * 16 + 16; ++r) {
            int node = row0 + r;
            if (node >= N_NODES) continue;   // wave-uniform
            if (lane < 40) {
                float a = 0.f;
                for (int k4 = 0; k4 < 32; ++k4) {
                    float4 zv = *(const float4*)&zt[r][k4 * 4];
                    float4 wv = *(const float4*)&wcs[lane * 136 + k4 * 4];
                    a += zv.x * wv.x + zv.y * wv.y + zv.z * wv.z + zv.w * wv.w;
                }
                out[(size_t)node * 40 + lane] = a;
            }
        }
    }
}

extern "C" void kernel_launch(void* const* d_in, const int* in_sizes, int n_in,
                              void* d_out, int out_size, void* d_ws, size_t ws_size,
                              hipStream_t stream) {
    const int* feats = (const int*)d_in[0];
    const int* src = (const int*)d_in[1];
    const int* dst = (const int*)d_in[2];
    const float* key_emb = (const float*)d_in[3];
    const float* val_emb = (const float*)d_in[4];
    const float* W1 = (const float*)d_in[5];
    const float* b1 = (const float*)d_in[6];
    const float* W2 = (const float*)d_in[7];
    const float* b2 = (const float*)d_in[8];
    const float* Wc = (const float*)d_in[9];
    float* out = (float*)d_out;

    char* ws = (char*)d_ws;
    auto carve = [&](size_t bytes) {
        char* p = ws;
        ws += (bytes + 255) & ~(size_t)255;
        return p;
    };
    float* h0 = (float*)carve((size_t)N_NODES * HID * 4);
    float* h1 = (float*)carve((size_t)N_NODES * HID * 4);
    int* counts = (int*)carve((size_t)N_NODES * 4);
    int* row_start = (int*)carve((size_t)N_NODES * 4);
    int* cursor = (int*)carve((size_t)N_NODES * 4);
    int* blockSums = (int*)carve(256 * 4);
    int* blockOff = (int*)carve(256 * 4);
    int* col = (int*)carve((size_t)N_EDGES * 4);

    hipMemsetAsync(counts, 0, (size_t)N_NODES * 4, stream);
    hipMemsetAsync(cursor, 0, (size_t)N_NODES * 4, stream);

    const int NB_SCAN = (N_NODES + 511) / 512;   // 98
    hist_kernel<<<(N_EDGES + 255) / 256, 256, 0, stream>>>(dst, counts);
    scan_block_kernel<<<NB_SCAN, 512, 0, stream>>>(counts, row_start, blockSums);
    scan_sums_kernel<<<1, 128, 0, stream>>>(blockSums, blockOff, NB_SCAN);
    add_off_kernel<<<(N_NODES + 255) / 256, 256, 0, stream>>>(row_start, blockOff);
    scatter_kernel<<<(N_EDGES + 255) / 256, 256, 0, stream>>>(src, dst, row_start, cursor, col);

    embed_kernel<<<(N_NODES * 32 + 255) / 256, 256, 0, stream>>>(feats, key_emb, val_emb, h0);

    const int NBLK = (N_NODES + 63) / 64;   // 782
    layer_kernel<false><<<NBLK, 256, 0, stream>>>(h0, h1, row_start, counts, col,
                                                  W1, b1, W2, b2, nullptr, nullptr);
    layer_kernel<false><<<NBLK, 256, 0, stream>>>(h1, h0, row_start, counts, col,
                                                  W1 + (size_t)HID * HID, b1 + HID,
                                                  W2 + (size_t)HID * HID, b2 + HID,
                                                  nullptr, nullptr);
    layer_kernel<true><<<NBLK, 256, 0, stream>>>(h0, nullptr, row_start, counts, col,
                                                 W1 + (size_t)2 * HID * HID, b1 + 2 * HID,
                                                 W2 + (size_t)2 * HID * HID, b2 + 2 * HID,
                                                 Wc, out);
}

// Round 3
// 789.609 us; speedup vs baseline: 1.0290x; 1.0290x over previous
//
#include <hip/hip_runtime.h>

#define N_NODES 50000
#define N_EDGES 800000
#define HID 128

// ---------------- CSR build ----------------
__global__ void hist_kernel(const int* __restrict__ dst, int* __restrict__ counts) {
    int e = blockIdx.x * 256 + threadIdx.x;
    if (e < N_EDGES) atomicAdd(&counts[dst[e]], 1);
}

__global__ void scan_block_kernel(const int* __restrict__ counts, int* __restrict__ excl,
                                  int* __restrict__ blockSums) {
    __shared__ int s[512];
    int t = threadIdx.x;
    int i = blockIdx.x * 512 + t;
    int v = (i < N_NODES) ? counts[i] : 0;
    s[t] = v;
    __syncthreads();
    for (int off = 1; off < 512; off <<= 1) {
        int add = (t >= off) ? s[t - off] : 0;
        __syncthreads();
        s[t] += add;
        __syncthreads();
    }
    if (i < N_NODES) excl[i] = s[t] - v;
    if (t == 511) blockSums[blockIdx.x] = s[511];
}

__global__ void scan_sums_kernel(const int* __restrict__ blockSums, int* __restrict__ blockOff,
                                 int nb) {
    __shared__ int s[128];
    int t = threadIdx.x;
    int v = (t < nb) ? blockSums[t] : 0;
    s[t] = v;
    __syncthreads();
    for (int off = 1; off < 128; off <<= 1) {
        int add = (t >= off) ? s[t - off] : 0;
        __syncthreads();
        s[t] += add;
        __syncthreads();
    }
    if (t < nb) blockOff[t] = s[t] - v;
}

__global__ void add_off_kernel(int* __restrict__ excl, const int* __restrict__ blockOff) {
    int i = blockIdx.x * 256 + threadIdx.x;
    if (i < N_NODES) excl[i] += blockOff[i >> 9];
}

__global__ void scatter_kernel(const int* __restrict__ src, const int* __restrict__ dst,
                               const int* __restrict__ row_start, int* __restrict__ cursor,
                               int* __restrict__ col) {
    int e = blockIdx.x * 256 + threadIdx.x;
    if (e < N_EDGES) {
        int d = dst[e];
        int p = atomicAdd(&cursor[d], 1);
        col[row_start[d] + p] = src[e];
    }
}

// ---------------- embedding ----------------
__global__ void embed_kernel(const int* __restrict__ feats, const float* __restrict__ key_emb,
                             const float* __restrict__ val_emb, float* __restrict__ h) {
    int idx = blockIdx.x * 256 + threadIdx.x;   // one float4 of one node row
    if (idx >= N_NODES * 32) return;
    int n = idx >> 5, q = idx & 31;
    int f0 = feats[2 * n], f1 = feats[2 * n + 1];
    float4 a = ((const float4*)key_emb)[f0 * 32 + q];
    float4 b = ((const float4*)val_emb)[f1 * 32 + q];
    float4 r;
    r.x = fmaxf(a.x + b.x, 0.f);
    r.y = fmaxf(a.y + b.y, 0.f);
    r.z = fmaxf(a.z + b.z, 0.f);
    r.w = fmaxf(a.w + b.w, 0.f);
    ((float4*)h)[idx] = r;
}

// ---------------- fused GIN layer: gather + 2-layer MLP ----------------
// 64-row tile in EXACTLY 32KB LDS -> 5 blocks/CU (160KB).
// __launch_bounds__(256,5) caps VGPR <=102 so LDS stays the binding limit.
__global__ __launch_bounds__(256, 5) void layer_kernel(
    const float* __restrict__ hin, float* __restrict__ hout,
    const int* __restrict__ row_start, const int* __restrict__ counts,
    const int* __restrict__ col,
    const float* __restrict__ W1, const float* __restrict__ b1,
    const float* __restrict__ W2, const float* __restrict__ b2) {
    __shared__ float zt[64][128];   // 32 KB exactly
    int t = threadIdx.x;
    int row0 = blockIdx.x * 64;
    int w = t >> 6, lane = t & 63;

    // ---- stage: z = h + sum_{u in N(node)} h[u], gathered straight into LDS ----
    {
        const float2* hp = (const float2*)hin;
        for (int r = w * 16; r < w * 16 + 16; ++r) {
            int node = row0 + r;
            float2 acc = make_float2(0.f, 0.f);
            if (node < N_NODES) {
                acc = hp[(size_t)node * 64 + lane];
                int s = row_start[node];
                int c = counts[node];
                int j = 0;
                for (; j + 4 <= c; j += 4) {
                    int u0 = col[s + j], u1 = col[s + j + 1];
                    int u2 = col[s + j + 2], u3 = col[s + j + 3];
                    float2 v0 = hp[(size_t)u0 * 64 + lane];
                    float2 v1 = hp[(size_t)u1 * 64 + lane];
                    float2 v2 = hp[(size_t)u2 * 64 + lane];
                    float2 v3 = hp[(size_t)u3 * 64 + lane];
                    acc.x += v0.x + v1.x + v2.x + v3.x;
                    acc.y += v0.y + v1.y + v2.y + v3.y;
                }
                for (; j < c; ++j) {
                    int u = col[s + j];
                    float2 v = hp[(size_t)u * 64 + lane];
                    acc.x += v.x;
                    acc.y += v.y;
                }
            }
            *(float2*)&zt[r][lane * 2] = acc;
        }
    }
    __syncthreads();

    int cg = t & 31, rg = t >> 5;   // 32 col-groups x 8 row-groups
    int c0 = cg * 4;
    float acc[4][8];

    // ---- phase 1: z1 = relu(z @ W1^T + b1) ----
    {
        float4 bv = ((const float4*)b1)[cg];
#pragma unroll
        for (int r = 0; r < 8; ++r) {
            acc[0][r] = bv.x; acc[1][r] = bv.y; acc[2][r] = bv.z; acc[3][r] = bv.w;
        }
        for (int k4 = 0; k4 < 32; ++k4) {
            float4 wv[4];
#pragma unroll
            for (int j = 0; j < 4; ++j)
                wv[j] = *(const float4*)&W1[(size_t)(c0 + j) * HID + k4 * 4];
#pragma unroll
            for (int r = 0; r < 8; ++r) {
                float4 zv = *(const float4*)&zt[rg * 8 + r][k4 * 4];
#pragma unroll
                for (int j = 0; j < 4; ++j)
                    acc[j][r] += zv.x * wv[j].x + zv.y * wv[j].y + zv.z * wv[j].z + zv.w * wv[j].w;
            }
        }
    }
    __syncthreads();
#pragma unroll
    for (int r = 0; r < 8; ++r) {
        float4 v = make_float4(fmaxf(acc[0][r], 0.f), fmaxf(acc[1][r], 0.f),
                               fmaxf(acc[2][r], 0.f), fmaxf(acc[3][r], 0.f));
        *(float4*)&zt[rg * 8 + r][c0] = v;
    }
    __syncthreads();

    // ---- phase 2: h = z1 @ W2^T + b2 ----
    {
        float4 bv = ((const float4*)b2)[cg];
#pragma unroll
        for (int r = 0; r < 8; ++r) {
            acc[0][r] = bv.x; acc[1][r] = bv.y; acc[2][r] = bv.z; acc[3][r] = bv.w;
        }
        for (int k4 = 0; k4 < 32; ++k4) {
            float4 wv[4];
#pragma unroll
            for (int j = 0; j < 4; ++j)
                wv[j] = *(const float4*)&W2[(size_t)(c0 + j) * HID + k4 * 4];
#pragma unroll
            for (int r = 0; r < 8; ++r) {
                float4 zv = *(const float4*)&zt[rg * 8 + r][k4 * 4];
#pragma unroll
                for (int j = 0; j < 4; ++j)
                    acc[j][r] += zv.x * wv[j].x + zv.y * wv[j].y + zv.z * wv[j].z + zv.w * wv[j].w;
            }
        }
    }
#pragma unroll
    for (int r = 0; r < 8; ++r) {
        int node = row0 + rg * 8 + r;
        if (node < N_NODES)
            *(float4*)&hout[(size_t)node * HID + c0] =
                make_float4(acc[0][r], acc[1][r], acc[2][r], acc[3][r]);
    }
}

// ---------------- classifier: out = h @ Wc^T  (Wc: 40x128) ----------------
__global__ __launch_bounds__(256) void cls_kernel(const float* __restrict__ h,
                                                  const float* __restrict__ Wc,
                                                  float* __restrict__ out) {
    __shared__ float wc[40 * 128];   // 20.5 KB
    int t = threadIdx.x;
    for (int i = t; i < 40 * 32; i += 256)
        ((float4*)wc)[i] = ((const float4*)Wc)[i];
    __syncthreads();
    int node = blockIdx.x * 32 + (t >> 3);
    int og = t & 7;   // 5 output columns per thread
    if (node >= N_NODES) return;
    float acc[5] = {0.f, 0.f, 0.f, 0.f, 0.f};
    const float4* hr = (const float4*)(h + (size_t)node * HID);
    for (int k4 = 0; k4 < 32; ++k4) {
        float4 zv = hr[k4];
#pragma unroll
        for (int i = 0; i < 5; ++i) {
            float4 w = *(const float4*)&wc[(og * 5 + i) * 128 + k4 * 4];
            acc[i] += zv.x * w.x + zv.y * w.y + zv.z * w.z + zv.w * w.w;
        }
    }
#pragma unroll
    for (int i = 0; i < 5; ++i) out[(size_t)node * 40 + og * 5 + i] = acc[i];
}

extern "C" void kernel_launch(void* const* d_in, const int* in_sizes, int n_in,
                              void* d_out, int out_size, void* d_ws, size_t ws_size,
                              hipStream_t stream) {
    const int* feats = (const int*)d_in[0];
    const int* src = (const int*)d_in[1];
    const int* dst = (const int*)d_in[2];
    const float* key_emb = (const float*)d_in[3];
    const float* val_emb = (const float*)d_in[4];
    const float* W1 = (const float*)d_in[5];
    const float* b1 = (const float*)d_in[6];
    const float* W2 = (const float*)d_in[7];
    const float* b2 = (const float*)d_in[8];
    const float* Wc = (const float*)d_in[9];
    float* out = (float*)d_out;

    char* ws = (char*)d_ws;
    auto carve = [&](size_t bytes) {
        char* p = ws;
        ws += (bytes + 255) & ~(size_t)255;
        return p;
    };
    float* h0 = (float*)carve((size_t)N_NODES * HID * 4);
    float* h1 = (float*)carve((size_t)N_NODES * HID * 4);
    int* counts = (int*)carve((size_t)N_NODES * 4);
    int* row_start = (int*)carve((size_t)N_NODES * 4);
    int* cursor = (int*)carve((size_t)N_NODES * 4);
    int* blockSums = (int*)carve(256 * 4);
    int* blockOff = (int*)carve(256 * 4);
    int* col = (int*)carve((size_t)N_EDGES * 4);

    hipMemsetAsync(counts, 0, (size_t)N_NODES * 4, stream);
    hipMemsetAsync(cursor, 0, (size_t)N_NODES * 4, stream);

    const int NB_SCAN = (N_NODES + 511) / 512;   // 98
    hist_kernel<<<(N_EDGES + 255) / 256, 256, 0, stream>>>(dst, counts);
    scan_block_kernel<<<NB_SCAN, 512, 0, stream>>>(counts, row_start, blockSums);
    scan_sums_kernel<<<1, 128, 0, stream>>>(blockSums, blockOff, NB_SCAN);
    add_off_kernel<<<(N_NODES + 255) / 256, 256, 0, stream>>>(row_start, blockOff);
    scatter_kernel<<<(N_EDGES + 255) / 256, 256, 0, stream>>>(src, dst, row_start, cursor, col);

    embed_kernel<<<(N_NODES * 32 + 255) / 256, 256, 0, stream>>>(feats, key_emb, val_emb, h0);

    const int NBLK = (N_NODES + 63) / 64;   // 782
    layer_kernel<<<NBLK, 256, 0, stream>>>(h0, h1, row_start, counts, col,
                                           W1, b1, W2, b2);
    layer_kernel<<<NBLK, 256, 0, stream>>>(h1, h0, row_start, counts, col,
                                           W1 + (size_t)HID * HID, b1 + HID,
                                           W2 + (size_t)HID * HID, b2 + HID);
    layer_kernel<<<NBLK, 256, 0, stream>>>(h0, h1, row_start, counts, col,
                                           W1 + (size_t)2 * HID * HID, b1 + 2 * HID,
                                           W2 + (size_t)2 * HID * HID, b2 + 2 * HID);
    cls_kernel<<<(N_NODES + 31) / 32, 256, 0, stream>>>(h1, Wc, out);
}

// Round 4
// 642.986 us; speedup vs baseline: 1.2637x; 1.2280x over previous
//
#include <hip/hip_runtime.h>

#define N_NODES 50000
#define N_PAD 50048      // rows padded to multiple of 64 so MLP needs no row guards
#define N_EDGES 800000
#define HID 128

typedef unsigned int uint;

// ---- bf16 pack/unpack (RNE) ----
__device__ inline uint f2bf_pair(float x, float y) {
    uint ux = __float_as_uint(x);
    uint uy = __float_as_uint(y);
    ux = (ux + 0x7FFFu + ((ux >> 16) & 1u)) >> 16;
    uy = (uy + 0x7FFFu + ((uy >> 16) & 1u)) >> 16;
    return ux | (uy << 16);
}
__device__ inline float bf_lo(uint v) { return __uint_as_float(v << 16); }
__device__ inline float bf_hi(uint v) { return __uint_as_float(v & 0xFFFF0000u); }

// ---------------- CSR build ----------------
__global__ void hist_kernel(const int* __restrict__ dst, int* __restrict__ counts) {
    int e = blockIdx.x * 256 + threadIdx.x;
    if (e < N_EDGES) atomicAdd(&counts[dst[e]], 1);
}

__global__ void scan_block_kernel(const int* __restrict__ counts, int* __restrict__ excl,
                                  int* __restrict__ blockSums) {
    __shared__ int s[512];
    int t = threadIdx.x;
    int i = blockIdx.x * 512 + t;
    int v = (i < N_NODES) ? counts[i] : 0;
    s[t] = v;
    __syncthreads();
    for (int off = 1; off < 512; off <<= 1) {
        int add = (t >= off) ? s[t - off] : 0;
        __syncthreads();
        s[t] += add;
        __syncthreads();
    }
    if (i < N_NODES) excl[i] = s[t] - v;
    if (t == 511) blockSums[blockIdx.x] = s[511];
}

__global__ void scan_sums_kernel(const int* __restrict__ blockSums, int* __restrict__ blockOff,
                                 int nb) {
    __shared__ int s[128];
    int t = threadIdx.x;
    int v = (t < nb) ? blockSums[t] : 0;
    s[t] = v;
    __syncthreads();
    for (int off = 1; off < 128; off <<= 1) {
        int add = (t >= off) ? s[t - off] : 0;
        __syncthreads();
        s[t] += add;
        __syncthreads();
    }
    if (t < nb) blockOff[t] = s[t] - v;
}

__global__ void add_off_kernel(int* __restrict__ excl, const int* __restrict__ blockOff) {
    int i = blockIdx.x * 256 + threadIdx.x;
    if (i < N_NODES) excl[i] += blockOff[i >> 9];
}

__global__ void scatter_kernel(const int* __restrict__ src, const int* __restrict__ dst,
                               const int* __restrict__ row_start, int* __restrict__ cursor,
                               int* __restrict__ col) {
    int e = blockIdx.x * 256 + threadIdx.x;
    if (e < N_EDGES) {
        int d = dst[e];
        int p = atomicAdd(&cursor[d], 1);
        col[row_start[d] + p] = src[e];
    }
}

// ---------------- embedding -> bf16 h ----------------
__global__ void embed_kernel(const int* __restrict__ feats, const float* __restrict__ key_emb,
                             const float* __restrict__ val_emb, uint* __restrict__ h) {
    int idx = blockIdx.x * 256 + threadIdx.x;   // one float4-pair (4 feats) of one node row
    if (idx >= N_NODES * 32) return;
    int n = idx >> 5, q = idx & 31;
    int f0 = feats[2 * n], f1 = feats[2 * n + 1];
    float4 a = ((const float4*)key_emb)[f0 * 32 + q];
    float4 b = ((const float4*)val_emb)[f1 * 32 + q];
    float r0 = fmaxf(a.x + b.x, 0.f), r1 = fmaxf(a.y + b.y, 0.f);
    float r2 = fmaxf(a.z + b.z, 0.f), r3 = fmaxf(a.w + b.w, 0.f);
    uint2 o;
    o.x = f2bf_pair(r0, r1);
    o.y = f2bf_pair(r2, r3);
    *(uint2*)&h[(size_t)n * 64 + q * 2] = o;
}

// ---------------- GIN aggregation: z = h + sum_{u in N(n)} h[u] (bf16 io, fp32 acc) ----
// one wave per node; lane covers 2 bf16 features (one dword)
__global__ __launch_bounds__(256) void agg_kernel(const uint* __restrict__ hb,
                                                  uint* __restrict__ zb,
                                                  const int* __restrict__ row_start,
                                                  const int* __restrict__ counts,
                                                  const int* __restrict__ col) {
    int node = blockIdx.x * 4 + (threadIdx.x >> 6);
    int lane = threadIdx.x & 63;
    uint hv = hb[(size_t)node * 64 + lane];
    float ax = bf_lo(hv), ay = bf_hi(hv);
    int s = __builtin_amdgcn_readfirstlane(row_start[node]);
    int c = __builtin_amdgcn_readfirstlane(counts[node]);
    int j = 0;
    for (; j + 4 <= c; j += 4) {
        int u0 = col[s + j], u1 = col[s + j + 1];
        int u2 = col[s + j + 2], u3 = col[s + j + 3];
        uint v0 = hb[(size_t)u0 * 64 + lane];
        uint v1 = hb[(size_t)u1 * 64 + lane];
        uint v2 = hb[(size_t)u2 * 64 + lane];
        uint v3 = hb[(size_t)u3 * 64 + lane];
        ax += (bf_lo(v0) + bf_lo(v1)) + (bf_lo(v2) + bf_lo(v3));
        ay += (bf_hi(v0) + bf_hi(v1)) + (bf_hi(v2) + bf_hi(v3));
    }
    for (; j < c; ++j) {
        int u = col[s + j];
        uint v = hb[(size_t)u * 64 + lane];
        ax += bf_lo(v);
        ay += bf_hi(v);
    }
    zb[(size_t)node * 64 + lane] = f2bf_pair(ax, ay);
}

// ---------------- 2-layer MLP: h = relu(z@W1^T + b1)@W2^T + b2 (bf16 io) --------
// 64-row tile, fp32 LDS; thread = 4 cols x 8 rows register block
__global__ __launch_bounds__(256, 5) void mlp_kernel(
    const uint* __restrict__ zb, uint* __restrict__ hout,
    const float* __restrict__ W1, const float* __restrict__ b1,
    const float* __restrict__ W2, const float* __restrict__ b2) {
    __shared__ float zt[64][128];   // 32 KB
    int t = threadIdx.x;
    int row0 = blockIdx.x * 64;

    // stage z tile: bf16 -> fp32 LDS (pad rows are garbage but harmless)
    {
        const uint2* z2 = (const uint2*)(zb + (size_t)row0 * 64);
        float4* zt4 = (float4*)&zt[0][0];
        for (int i = t; i < 2048; i += 256) {
            uint2 v = z2[i];
            zt4[i] = make_float4(bf_lo(v.x), bf_hi(v.x), bf_lo(v.y), bf_hi(v.y));
        }
    }
    __syncthreads();

    int cg = t & 31, rg = t >> 5;   // 32 col-groups x 8 row-groups
    int c0 = cg * 4;
    float acc[4][8];

    // ---- phase 1: z1 = relu(z @ W1^T + b1) ----
    {
        float4 bv = ((const float4*)b1)[cg];
#pragma unroll
        for (int r = 0; r < 8; ++r) {
            acc[0][r] = bv.x; acc[1][r] = bv.y; acc[2][r] = bv.z; acc[3][r] = bv.w;
        }
        for (int k4 = 0; k4 < 32; ++k4) {
            float4 wv[4];
#pragma unroll
            for (int j = 0; j < 4; ++j)
                wv[j] = *(const float4*)&W1[(size_t)(c0 + j) * HID + k4 * 4];
#pragma unroll
            for (int r = 0; r < 8; ++r) {
                float4 zv = *(const float4*)&zt[rg * 8 + r][k4 * 4];
#pragma unroll
                for (int j = 0; j < 4; ++j)
                    acc[j][r] += zv.x * wv[j].x + zv.y * wv[j].y + zv.z * wv[j].z + zv.w * wv[j].w;
            }
        }
    }
    __syncthreads();
#pragma unroll
    for (int r = 0; r < 8; ++r) {
        float4 v = make_float4(fmaxf(acc[0][r], 0.f), fmaxf(acc[1][r], 0.f),
                               fmaxf(acc[2][r], 0.f), fmaxf(acc[3][r], 0.f));
        *(float4*)&zt[rg * 8 + r][c0] = v;
    }
    __syncthreads();

    // ---- phase 2: h = z1 @ W2^T + b2 ----
    {
        float4 bv = ((const float4*)b2)[cg];
#pragma unroll
        for (int r = 0; r < 8; ++r) {
            acc[0][r] = bv.x; acc[1][r] = bv.y; acc[2][r] = bv.z; acc[3][r] = bv.w;
        }
        for (int k4 = 0; k4 < 32; ++k4) {
            float4 wv[4];
#pragma unroll
            for (int j = 0; j < 4; ++j)
                wv[j] = *(const float4*)&W2[(size_t)(c0 + j) * HID + k4 * 4];
#pragma unroll
            for (int r = 0; r < 8; ++r) {
                float4 zv = *(const float4*)&zt[rg * 8 + r][k4 * 4];
#pragma unroll
                for (int j = 0; j < 4; ++j)
                    acc[j][r] += zv.x * wv[j].x + zv.y * wv[j].y + zv.z * wv[j].z + zv.w * wv[j].w;
            }
        }
    }
#pragma unroll
    for (int r = 0; r < 8; ++r) {
        int node = row0 + rg * 8 + r;   // pad rows exist in buffer; no guard needed
        uint2 o;
        o.x = f2bf_pair(acc[0][r], acc[1][r]);
        o.y = f2bf_pair(acc[2][r], acc[3][r]);
        *(uint2*)&hout[(size_t)node * 64 + cg * 2] = o;
    }
}

// ---------------- classifier: out = h @ Wc^T  (Wc: 40x128, h bf16) ----------------
__global__ __launch_bounds__(256) void cls_kernel(const uint* __restrict__ hb,
                                                  const float* __restrict__ Wc,
                                                  float* __restrict__ out) {
    __shared__ float wcs[40 * 132];   // padded stride vs 8-way bank conflict
    int t = threadIdx.x;
    for (int i = t; i < 40 * 32; i += 256) {
        int c = i >> 5, q = i & 31;
        *(float4*)&wcs[c * 132 + q * 4] = ((const float4*)Wc)[i];
    }
    __syncthreads();
    int node = blockIdx.x * 32 + (t >> 3);
    int og = t & 7;   // 5 output columns per thread
    if (node >= N_NODES) return;
    float acc[5] = {0.f, 0.f, 0.f, 0.f, 0.f};
    const uint2* hr = (const uint2*)(hb + (size_t)node * 64);
    for (int k = 0; k < 32; ++k) {
        uint2 v = hr[k];
        float z0 = bf_lo(v.x), z1 = bf_hi(v.x), z2 = bf_lo(v.y), z3 = bf_hi(v.y);
#pragma unroll
        for (int i = 0; i < 5; ++i) {
            float4 w = *(const float4*)&wcs[(og * 5 + i) * 132 + k * 4];
            acc[i] += z0 * w.x + z1 * w.y + z2 * w.z + z3 * w.w;
        }
    }
#pragma unroll
    for (int i = 0; i < 5; ++i) out[(size_t)node * 40 + og * 5 + i] = acc[i];
}

extern "C" void kernel_launch(void* const* d_in, const int* in_sizes, int n_in,
                              void* d_out, int out_size, void* d_ws, size_t ws_size,
                              hipStream_t stream) {
    const int* feats = (const int*)d_in[0];
    const int* src = (const int*)d_in[1];
    const int* dst = (const int*)d_in[2];
    const float* key_emb = (const float*)d_in[3];
    const float* val_emb = (const float*)d_in[4];
    const float* W1 = (const float*)d_in[5];
    const float* b1 = (const float*)d_in[6];
    const float* W2 = (const float*)d_in[7];
    const float* b2 = (const float*)d_in[8];
    const float* Wc = (const float*)d_in[9];
    float* out = (float*)d_out;

    char* ws = (char*)d_ws;
    auto carve = [&](size_t bytes) {
        char* p = ws;
        ws += (bytes + 255) & ~(size_t)255;
        return p;
    };
    uint* h0 = (uint*)carve((size_t)N_PAD * 64 * 4);
    uint* h1 = (uint*)carve((size_t)N_PAD * 64 * 4);
    uint* zb = (uint*)carve((size_t)N_PAD * 64 * 4);
    int* counts = (int*)carve((size_t)N_NODES * 4);
    int* row_start = (int*)carve((size_t)N_NODES * 4);
    int* cursor = (int*)carve((size_t)N_NODES * 4);
    int* blockSums = (int*)carve(256 * 4);
    int* blockOff = (int*)carve(256 * 4);
    int* col = (int*)carve((size_t)N_EDGES * 4);

    hipMemsetAsync(counts, 0, (size_t)N_NODES * 4, stream);
    hipMemsetAsync(cursor, 0, (size_t)N_NODES * 4, stream);

    const int NB_SCAN = (N_NODES + 511) / 512;   // 98
    hist_kernel<<<(N_EDGES + 255) / 256, 256, 0, stream>>>(dst, counts);
    scan_block_kernel<<<NB_SCAN, 512, 0, stream>>>(counts, row_start, blockSums);
    scan_sums_kernel<<<1, 128, 0, stream>>>(blockSums, blockOff, NB_SCAN);
    add_off_kernel<<<(N_NODES + 255) / 256, 256, 0, stream>>>(row_start, blockOff);
    scatter_kernel<<<(N_EDGES + 255) / 256, 256, 0, stream>>>(src, dst, row_start, cursor, col);

    embed_kernel<<<(N_NODES * 32 + 255) / 256, 256, 0, stream>>>(feats, key_emb, val_emb, h0);

    const int NBLK_MLP = (N_PAD + 63) / 64;      // 782
    const int NBLK_AGG = (N_NODES + 3) / 4;      // 12500

    agg_kernel<<<NBLK_AGG, 256, 0, stream>>>(h0, zb, row_start, counts, col);
    mlp_kernel<<<NBLK_MLP, 256, 0, stream>>>(zb, h1, W1, b1, W2, b2);
    agg_kernel<<<NBLK_AGG, 256, 0, stream>>>(h1, zb, row_start, counts, col);
    mlp_kernel<<<NBLK_MLP, 256, 0, stream>>>(zb, h0,
                                             W1 + (size_t)HID * HID, b1 + HID,
                                             W2 + (size_t)HID * HID, b2 + HID);
    agg_kernel<<<NBLK_AGG, 256, 0, stream>>>(h0, zb, row_start, counts, col);
    mlp_kernel<<<NBLK_MLP, 256, 0, stream>>>(zb, h1,
                                             W1 + (size_t)2 * HID * HID, b1 + 2 * HID,
                                             W2 + (size_t)2 * HID * HID, b2 + 2 * HID);
    cls_kernel<<<(N_NODES + 31) / 32, 256, 0, stream>>>(h1, Wc, out);
}

// Round 7
// 382.597 us; speedup vs baseline: 2.1237x; 1.6806x over previous
//
#include <hip/hip_runtime.h>

#define N_NODES 50000
#define N_PAD 50048      // rows padded to multiple of 64 so MLP needs no row guards
#define N_EDGES 800000
#define HID 128

typedef unsigned int uint;
typedef unsigned short ushort;
typedef __attribute__((ext_vector_type(8))) short short8;   // 8 bf16 = 4 VGPRs
typedef __attribute__((ext_vector_type(4))) float f32x4;

// ---- bf16 pack/unpack (RNE) ----
__device__ inline uint f2bf_pair(float x, float y) {
    uint ux = __float_as_uint(x);
    uint uy = __float_as_uint(y);
    ux = (ux + 0x7FFFu + ((ux >> 16) & 1u)) >> 16;
    uy = (uy + 0x7FFFu + ((uy >> 16) & 1u)) >> 16;
    return ux | (uy << 16);
}
__device__ inline float bf_lo(uint v) { return __uint_as_float(v << 16); }
__device__ inline float bf_hi(uint v) { return __uint_as_float(v & 0xFFFF0000u); }

// ---------------- CSR build ----------------
__global__ void hist_kernel(const int* __restrict__ dst, int* __restrict__ counts) {
    int e = blockIdx.x * 256 + threadIdx.x;
    if (e < N_EDGES) atomicAdd(&counts[dst[e]], 1);
}

__global__ void scan_block_kernel(const int* __restrict__ counts, int* __restrict__ excl,
                                  int* __restrict__ blockSums) {
    __shared__ int s[512];
    int t = threadIdx.x;
    int i = blockIdx.x * 512 + t;
    int v = (i < N_NODES) ? counts[i] : 0;
    s[t] = v;
    __syncthreads();
    for (int off = 1; off < 512; off <<= 1) {
        int add = (t >= off) ? s[t - off] : 0;
        __syncthreads();
        s[t] += add;
        __syncthreads();
    }
    if (i < N_NODES) excl[i] = s[t] - v;
    if (t == 511) blockSums[blockIdx.x] = s[511];
}

__global__ void scan_sums_kernel(const int* __restrict__ blockSums, int* __restrict__ blockOff,
                                 int nb) {
    __shared__ int s[128];
    int t = threadIdx.x;
    int v = (t < nb) ? blockSums[t] : 0;
    s[t] = v;
    __syncthreads();
    for (int off = 1; off < 128; off <<= 1) {
        int add = (t >= off) ? s[t - off] : 0;
        __syncthreads();
        s[t] += add;
        __syncthreads();
    }
    if (t < nb) blockOff[t] = s[t] - v;
}

__global__ void add_off_kernel(int* __restrict__ excl, const int* __restrict__ blockOff) {
    int i = blockIdx.x * 256 + threadIdx.x;
    if (i < N_NODES) excl[i] += blockOff[i >> 9];
}

__global__ void scatter_kernel(const int* __restrict__ src, const int* __restrict__ dst,
                               const int* __restrict__ row_start, int* __restrict__ cursor,
                               int* __restrict__ col) {
    int e = blockIdx.x * 256 + threadIdx.x;
    if (e < N_EDGES) {
        int d = dst[e];
        int p = atomicAdd(&cursor[d], 1);
        col[row_start[d] + p] = src[e];
    }
}

// ---------------- weights fp32 -> bf16 (once per launch) ----------------
__global__ void wconv_kernel(const float* __restrict__ W1, const float* __restrict__ W2,
                             uint* __restrict__ w1b, uint* __restrict__ w2b) {
    int i = blockIdx.x * 256 + threadIdx.x;   // bf16-pair index
    if (i < 3 * 128 * 64) {
        w1b[i] = f2bf_pair(W1[2 * i], W1[2 * i + 1]);
        w2b[i] = f2bf_pair(W2[2 * i], W2[2 * i + 1]);
    }
}

// ---------------- embedding -> bf16 h ----------------
__global__ void embed_kernel(const int* __restrict__ feats, const float* __restrict__ key_emb,
                             const float* __restrict__ val_emb, uint* __restrict__ h) {
    int idx = blockIdx.x * 256 + threadIdx.x;
    if (idx >= N_NODES * 32) return;
    int n = idx >> 5, q = idx & 31;
    int f0 = feats[2 * n], f1 = feats[2 * n + 1];
    float4 a = ((const float4*)key_emb)[f0 * 32 + q];
    float4 b = ((const float4*)val_emb)[f1 * 32 + q];
    float r0 = fmaxf(a.x + b.x, 0.f), r1 = fmaxf(a.y + b.y, 0.f);
    float r2 = fmaxf(a.z + b.z, 0.f), r3 = fmaxf(a.w + b.w, 0.f);
    uint2 o;
    o.x = f2bf_pair(r0, r1);
    o.y = f2bf_pair(r2, r3);
    *(uint2*)&h[(size_t)n * 64 + q * 2] = o;
}

// ---------------- GIN aggregation: z = h + sum_{u in N(n)} h[u] (bf16 io, fp32 acc) ----
__global__ __launch_bounds__(256) void agg_kernel(const uint* __restrict__ hb,
                                                  uint* __restrict__ zb,
                                                  const int* __restrict__ row_start,
                                                  const int* __restrict__ counts,
                                                  const int* __restrict__ col) {
    int node = blockIdx.x * 4 + (threadIdx.x >> 6);
    int lane = threadIdx.x & 63;
    uint hv = hb[(size_t)node * 64 + lane];
    float ax = bf_lo(hv), ay = bf_hi(hv);
    int s = __builtin_amdgcn_readfirstlane(row_start[node]);
    int c = __builtin_amdgcn_readfirstlane(counts[node]);
    int j = 0;
    for (; j + 4 <= c; j += 4) {
        int u0 = col[s + j], u1 = col[s + j + 1];
        int u2 = col[s + j + 2], u3 = col[s + j + 3];
        uint v0 = hb[(size_t)u0 * 64 + lane];
        uint v1 = hb[(size_t)u1 * 64 + lane];
        uint v2 = hb[(size_t)u2 * 64 + lane];
        uint v3 = hb[(size_t)u3 * 64 + lane];
        ax += (bf_lo(v0) + bf_lo(v1)) + (bf_lo(v2) + bf_lo(v3));
        ay += (bf_hi(v0) + bf_hi(v1)) + (bf_hi(v2) + bf_hi(v3));
    }
    for (; j < c; ++j) {
        int u = col[s + j];
        uint v = hb[(size_t)u * 64 + lane];
        ax += bf_lo(v);
        ay += bf_hi(v);
    }
    zb[(size_t)node * 64 + lane] = f2bf_pair(ax, ay);
}

// ---------------- MFMA 2-layer MLP: h = relu(z@W1^T + b1)@W2^T + b2 ----------------
// 4 waves/block; wave w owns rows [blk*64 + w*16, +16), all 128 cols.
// mfma_f32_16x16x32_bf16: A lane l holds z[row0+w*16+(l&15)][ks*32+(l>>4)*8 ..+8];
// B identical addressing on row-major W (out = z@W^T); C/D col=l&15, row=(l>>4)*4+q.
__global__ __launch_bounds__(256) void mlp_kernel(
    const uint* __restrict__ zb, uint* __restrict__ hout,
    const uint* __restrict__ w1b, const float* __restrict__ b1,
    const uint* __restrict__ w2b, const float* __restrict__ b2) {
    __shared__ float z1[64][132];   // stride 132 -> conflict-free, 33 KB
    int t = threadIdx.x;
    int w = t >> 6, l = t & 63;
    int lm = l & 15, lk = l >> 4;
    int row0 = blockIdx.x * 64;

    f32x4 acc[8];
    // ---- phase 1: z1 = relu(z @ W1^T + b1) ----
#pragma unroll
    for (int n = 0; n < 8; ++n) {
        float bv = b1[n * 16 + lm];
        acc[n] = (f32x4){bv, bv, bv, bv};
    }
#pragma unroll
    for (int ks = 0; ks < 4; ++ks) {
        uint4 av = *(const uint4*)(zb + (size_t)(row0 + w * 16 + lm) * 64 + ks * 16 + lk * 4);
        short8 a = *(short8*)&av;
#pragma unroll
        for (int n = 0; n < 8; ++n) {
            uint4 bv4 = *(const uint4*)(w1b + (size_t)(n * 16 + lm) * 64 + ks * 16 + lk * 4);
            short8 b = *(short8*)&bv4;
            acc[n] = __builtin_amdgcn_mfma_f32_16x16x32_bf16(a, b, acc[n], 0, 0, 0);
        }
    }
#pragma unroll
    for (int n = 0; n < 8; ++n)
#pragma unroll
        for (int q = 0; q < 4; ++q)
            z1[w * 16 + lk * 4 + q][n * 16 + lm] = fmaxf(acc[n][q], 0.f);
    __syncthreads();

    // ---- phase 2: h = z1 @ W2^T + b2 ----
#pragma unroll
    for (int n = 0; n < 8; ++n) {
        float bv = b2[n * 16 + lm];
        acc[n] = (f32x4){bv, bv, bv, bv};
    }
#pragma unroll
    for (int ks = 0; ks < 4; ++ks) {
        float4 f0 = *(const float4*)&z1[w * 16 + lm][ks * 32 + lk * 8];
        float4 f1 = *(const float4*)&z1[w * 16 + lm][ks * 32 + lk * 8 + 4];
        uint4 ua;
        ua.x = f2bf_pair(f0.x, f0.y);
        ua.y = f2bf_pair(f0.z, f0.w);
        ua.z = f2bf_pair(f1.x, f1.y);
        ua.w = f2bf_pair(f1.z, f1.w);
        short8 a = *(short8*)&ua;
#pragma unroll
        for (int n = 0; n < 8; ++n) {
            uint4 bv4 = *(const uint4*)(w2b + (size_t)(n * 16 + lm) * 64 + ks * 16 + lk * 4);
            short8 b = *(short8*)&bv4;
            acc[n] = __builtin_amdgcn_mfma_f32_16x16x32_bf16(a, b, acc[n], 0, 0, 0);
        }
    }
    // stage result in LDS (own wave's rows; in-order DS per wave makes this safe)
#pragma unroll
    for (int n = 0; n < 8; ++n)
#pragma unroll
        for (int q = 0; q < 4; ++q)
            z1[w * 16 + lk * 4 + q][n * 16 + lm] = acc[n][q];
    __syncthreads();
    // repack to bf16, coalesced uint2 stores — FULL 64x128 tile (2048 uint2 groups)
    for (int i = t; i < 2048; i += 256) {
        int row = i >> 5, j = i & 31;
        float4 v = *(const float4*)&z1[row][j * 4];
        uint2 o;
        o.x = f2bf_pair(v.x, v.y);
        o.y = f2bf_pair(v.z, v.w);
        *(uint2*)&hout[(size_t)(row0 + row) * 64 + j * 2] = o;
    }
}

// ---------------- classifier: out = h @ Wc^T  (Wc: 40x128, h bf16) ----------------
__global__ __launch_bounds__(256) void cls_kernel(const uint* __restrict__ hb,
                                                  const float* __restrict__ Wc,
                                                  float* __restrict__ out) {
    __shared__ float wcs[40 * 132];
    int t = threadIdx.x;
    for (int i = t; i < 40 * 32; i += 256) {
        int c = i >> 5, q = i & 31;
        *(float4*)&wcs[c * 132 + q * 4] = ((const float4*)Wc)[i];
    }
    __syncthreads();
    int node = blockIdx.x * 32 + (t >> 3);
    int og = t & 7;
    if (node >= N_NODES) return;
    float acc[5] = {0.f, 0.f, 0.f, 0.f, 0.f};
    const uint2* hr = (const uint2*)(hb + (size_t)node * 64);
    for (int k = 0; k < 32; ++k) {
        uint2 v = hr[k];
        float z0 = bf_lo(v.x), z1 = bf_hi(v.x), z2 = bf_lo(v.y), z3 = bf_hi(v.y);
#pragma unroll
        for (int i = 0; i < 5; ++i) {
            float4 w = *(const float4*)&wcs[(og * 5 + i) * 132 + k * 4];
            acc[i] += z0 * w.x + z1 * w.y + z2 * w.z + z3 * w.w;
        }
    }
#pragma unroll
    for (int i = 0; i < 5; ++i) out[(size_t)node * 40 + og * 5 + i] = acc[i];
}

extern "C" void kernel_launch(void* const* d_in, const int* in_sizes, int n_in,
                              void* d_out, int out_size, void* d_ws, size_t ws_size,
                              hipStream_t stream) {
    const int* feats = (const int*)d_in[0];
    const int* src = (const int*)d_in[1];
    const int* dst = (const int*)d_in[2];
    const float* key_emb = (const float*)d_in[3];
    const float* val_emb = (const float*)d_in[4];
    const float* W1 = (const float*)d_in[5];
    const float* b1 = (const float*)d_in[6];
    const float* W2 = (const float*)d_in[7];
    const float* b2 = (const float*)d_in[8];
    const float* Wc = (const float*)d_in[9];
    float* out = (float*)d_out;

    char* ws = (char*)d_ws;
    auto carve = [&](size_t bytes) {
        char* p = ws;
        ws += (bytes + 255) & ~(size_t)255;
        return p;
    };
    uint* h0 = (uint*)carve((size_t)N_PAD * 64 * 4);
    uint* h1 = (uint*)carve((size_t)N_PAD * 64 * 4);
    uint* zb = (uint*)carve((size_t)N_PAD * 64 * 4);
    uint* w1b = (uint*)carve((size_t)3 * 128 * 64 * 4);
    uint* w2b = (uint*)carve((size_t)3 * 128 * 64 * 4);
    int* counts = (int*)carve((size_t)N_NODES * 4);
    int* row_start = (int*)carve((size_t)N_NODES * 4);
    int* cursor = (int*)carve((size_t)N_NODES * 4);
    int* blockSums = (int*)carve(256 * 4);
    int* blockOff = (int*)carve(256 * 4);
    int* col = (int*)carve((size_t)N_EDGES * 4);

    hipMemsetAsync(counts, 0, (size_t)N_NODES * 4, stream);
    hipMemsetAsync(cursor, 0, (size_t)N_NODES * 4, stream);

    const int NB_SCAN = (N_NODES + 511) / 512;   // 98
    hist_kernel<<<(N_EDGES + 255) / 256, 256, 0, stream>>>(dst, counts);
    scan_block_kernel<<<NB_SCAN, 512, 0, stream>>>(counts, row_start, blockSums);
    scan_sums_kernel<<<1, 128, 0, stream>>>(blockSums, blockOff, NB_SCAN);
    add_off_kernel<<<(N_NODES + 255) / 256, 256, 0, stream>>>(row_start, blockOff);
    scatter_kernel<<<(N_EDGES + 255) / 256, 256, 0, stream>>>(src, dst, row_start, cursor, col);

    wconv_kernel<<<(3 * 128 * 64 + 255) / 256, 256, 0, stream>>>(W1, W2, w1b, w2b);
    embed_kernel<<<(N_NODES * 32 + 255) / 256, 256, 0, stream>>>(feats, key_emb, val_emb, h0);

    const int NBLK_MLP = (N_PAD + 63) / 64;      // 782
    const int NBLK_AGG = (N_NODES + 3) / 4;      // 12500

    agg_kernel<<<NBLK_AGG, 256, 0, stream>>>(h0, zb, row_start, counts, col);
    mlp_kernel<<<NBLK_MLP, 256, 0, stream>>>(zb, h1, w1b, b1, w2b, b2);
    agg_kernel<<<NBLK_AGG, 256, 0, stream>>>(h1, zb, row_start, counts, col);
    mlp_kernel<<<NBLK_MLP, 256, 0, stream>>>(zb, h0, w1b + 128 * 64, b1 + HID,
                                             w2b + 128 * 64, b2 + HID);
    agg_kernel<<<NBLK_AGG, 256, 0, stream>>>(h0, zb, row_start, counts, col);
    mlp_kernel<<<NBLK_MLP, 256, 0, stream>>>(zb, h1, w1b + 2 * 128 * 64, b1 + 2 * HID,
                                             w2b + 2 * 128 * 64, b2 + 2 * HID);
    cls_kernel<<<(N_NODES + 31) / 32, 256, 0, stream>>>(h1, Wc, out);
}